// Round 8
// baseline (236.764 us; speedup 1.0000x reference)
//
#include <hip/hip_runtime.h>
#include <math.h>

#define C_DIM 256
#define N_DIM 4096
#define NHEAD 8

using bf16x8 = __attribute__((ext_vector_type(8))) short;   // 8 bf16 = 4 VGPRs
using f32x16 = __attribute__((ext_vector_type(16))) float;  // 32x32 MFMA acc

__device__ __forceinline__ short f32_to_bf16(float a) {
    return (short)((__float_as_uint(a) + 0x8000u) >> 16);
}
__device__ __forceinline__ float bf16_to_f32(unsigned short u) {
    return __uint_as_float(((unsigned)u) << 16);
}
// lo16 = hi16(a), hi16 = hi16(b): single v_perm_b32 (truncation rounding)
__device__ __forceinline__ unsigned pack_trunc(float a, float b) {
    return __builtin_amdgcn_perm(__float_as_uint(b), __float_as_uint(a), 0x07060302u);
}

// Fragment-order ("swizzled") layout for 256-col planes, index in shorts.
// Per 32-row tile: [16 kc][2 q2][32 row][8 c]
__device__ __forceinline__ int SWZ(int m, int c) {
    return (m >> 5) * 8192 + (c >> 4) * 512 + ((c >> 3) & 1) * 256 + (m & 31) * 8 + (c & 7);
}

// ---------------------------------------------------------------------------
// prep: z<4 -> transpose query/key [c][n] fp32 -> swizzled bf16 [n][c] planes
//       z==4 -> convert 4 weight planes fp32 -> swizzled bf16; zero gstats
// ---------------------------------------------------------------------------
__global__ __launch_bounds__(256) void prep(
    const float* __restrict__ query, const float* __restrict__ key,
    const float* __restrict__ qw, const float* __restrict__ kw,
    const float* __restrict__ vw, const float* __restrict__ ow,
    short* __restrict__ Qx, short* __restrict__ Kx, short* __restrict__ Wsw,
    float* __restrict__ gstats)
{
    const int t = threadIdx.x;
    if (blockIdx.z == 4) {
        const int p = blockIdx.y;
        if (blockIdx.x == 0 && p == 0 && t < 128) gstats[t] = 0.f;
        const float* src = (p == 0) ? qw : (p == 1) ? kw : (p == 2) ? vw : ow;
        const int idx = (blockIdx.x * 256 + t) * 4;
        const int o = idx >> 8, c = idx & 255;
        float4 v = *(const float4*)&src[idx];
        short* dst = Wsw + p * 65536 + SWZ(o, c);
        dst[0] = f32_to_bf16(v.x); dst[1] = f32_to_bf16(v.y);
        dst[2] = f32_to_bf16(v.z); dst[3] = f32_to_bf16(v.w);
        return;
    }
    __shared__ short Ts[64][72];
    const int z = blockIdx.z;
    const float* in = (z < 2) ? query : key;
    short* out = ((z < 2) ? Qx : Kx) + (size_t)(z & 1) * N_DIM * C_DIM;
    const size_t ibase = (size_t)(z & 1) * C_DIM * N_DIM;
    const int n0 = blockIdx.x * 64, c0 = blockIdx.y * 64;
    const int cl = t >> 4, nl4 = (t & 15) * 4;
#pragma unroll
    for (int p = 0; p < 4; ++p) {
        const int c = cl + p * 16;
        float4 v = *(const float4*)&in[ibase + (size_t)(c0 + c) * N_DIM + n0 + nl4];
        Ts[nl4 + 0][c] = f32_to_bf16(v.x);
        Ts[nl4 + 1][c] = f32_to_bf16(v.y);
        Ts[nl4 + 2][c] = f32_to_bf16(v.z);
        Ts[nl4 + 3][c] = f32_to_bf16(v.w);
    }
    __syncthreads();
    const int nl = t >> 3, cg = t & 7;
#pragma unroll
    for (int half = 0; half < 2; ++half) {
        const int nloc = nl + half * 32;
        const int c = c0 + cg * 8;
        uint4 val = *(const uint4*)&Ts[nloc][cg * 8];
        *(uint4*)&out[SWZ(n0 + nloc, c)] = val;
    }
}

// ---------------------------------------------------------------------------
// QKV projection: z = proj*2 + batch. Block = 4 waves, 64n x 64o.
// proj 0/1 (Q/K): D = X.W^T -> swizzled head plane [n][d].
// proj 2   (V):   D = W.X   -> swizzled head plane [d-rows][k].
// ---------------------------------------------------------------------------
__global__ __launch_bounds__(256) void qkv_gemm(
    const short* __restrict__ Wsw, const short* __restrict__ Qx,
    const short* __restrict__ Kx,
    const float* __restrict__ q_b, const float* __restrict__ k_b,
    const float* __restrict__ v_b,
    short* __restrict__ Qt, short* __restrict__ Kt, short* __restrict__ Vt,
    float qscale)
{
    const int t = threadIdx.x, w = t >> 6, lane = t & 63;
    const int q2 = lane >> 5, l31 = lane & 31;
    const int proj = blockIdx.z >> 1, b = blockIdx.z & 1;
    const int n0 = blockIdx.x * 64 + (w >> 1) * 32;
    const int o0 = blockIdx.y * 64 + (w & 1) * 32;
    const short* X = ((proj == 0) ? Qx : Kx) + (size_t)b * N_DIM * C_DIM;
    const short* W = Wsw + proj * 65536;
    const float* bias = (proj == 0) ? q_b : (proj == 1) ? k_b : v_b;
    const int xbase = (n0 >> 5) * 8192 + q2 * 256 + l31 * 8;
    const int wbase = (o0 >> 5) * 8192 + q2 * 256 + l31 * 8;

    f32x16 acc;
#pragma unroll
    for (int r = 0; r < 16; ++r) acc[r] = 0.f;

#pragma unroll 4
    for (int kc = 0; kc < C_DIM; kc += 16) {
        bf16x8 xf = *(const bf16x8*)&X[xbase + (kc >> 4) * 512];
        bf16x8 wf = *(const bf16x8*)&W[wbase + (kc >> 4) * 512];
        if (proj == 2)
            acc = __builtin_amdgcn_mfma_f32_32x32x16_bf16(wf, xf, acc, 0, 0, 0);
        else
            acc = __builtin_amdgcn_mfma_f32_32x32x16_bf16(xf, wf, acc, 0, 0, 0);
    }

    const int head = o0 >> 5;
    if (proj < 2) {
        short* OH = ((proj == 0) ? Qt : Kt) + (size_t)(b * NHEAD + head) * N_DIM * 32;
        const float bi = bias[o0 + l31];
        const float sc = (proj == 0) ? qscale : 1.f;
        const int cbase = (n0 >> 5) * 1024 + (l31 >> 4) * 512 + ((l31 >> 3) & 1) * 256 + (l31 & 7);
#pragma unroll
        for (int r = 0; r < 16; ++r) {
            const int qs = (r & 3) + 8 * (r >> 2) + 4 * q2;
            OH[cbase + qs * 8] = f32_to_bf16((acc[r] + bi) * sc);
        }
    } else {
        short* VH = Vt + (size_t)(b * NHEAD + head) * N_DIM * 32;
        const int kbase = (n0 >> 5) * 1024 + (l31 >> 4) * 512 + ((l31 >> 3) & 1) * 256 + (l31 & 7);
#pragma unroll
        for (int r = 0; r < 16; ++r) {
            const int ds = (r & 3) + 8 * (r >> 2) + 4 * q2;
            VH[kbase + ds * 8] = f32_to_bf16(acc[r] + bias[o0 + ds]);
        }
    }
}

// ---------------------------------------------------------------------------
// Flash attention, swizzled operands, split-4 over keys. r7 main loop with
// one change: hoisted zero-C constant for the S MFMA (kills 16 movs/iter).
// ---------------------------------------------------------------------------
__global__ __launch_bounds__(256) void flash_mfma(
    const short* __restrict__ Qt, const short* __restrict__ Kt,
    const short* __restrict__ Vt, short* __restrict__ Opart,
    float* __restrict__ lpart)
{
    const int n0 = blockIdx.x * 128;
    const int h  = blockIdx.y;
    const int z  = blockIdx.z;
    const int b  = z >> 2, s = z & 3;
    const int CHUNK = N_DIM / 4;
    const int t = threadIdx.x, w = t >> 6, lane = t & 63;
    const int q2 = lane >> 5, l31 = lane & 31;
    const int q  = n0 + w * 32 + l31;
    const int bhp = b * NHEAD + h;
    const size_t hb = (size_t)bhp * N_DIM * 32;

    const int qoff = (q >> 5) * 1024 + q2 * 256 + (q & 31) * 8;
    bf16x8 Qf0 = *(const bf16x8*)&Qt[hb + qoff];
    bf16x8 Qf1 = *(const bf16x8*)&Qt[hb + qoff + 512];

    const f32x16 zc = {};

    int off = ((s * CHUNK) >> 5) * 1024 + q2 * 256 + l31 * 8;
    bf16x8 Kc0 = *(const bf16x8*)&Kt[hb + off];
    bf16x8 Kc1 = *(const bf16x8*)&Kt[hb + off + 512];
    bf16x8 Vc0 = *(const bf16x8*)&Vt[hb + off];
    bf16x8 Vc1 = *(const bf16x8*)&Vt[hb + off + 512];
    off += 1024;

    f32x16 Of;
#pragma unroll
    for (int r = 0; r < 16; ++r) Of[r] = 0.f;
    float ls = 0.f;

    for (int it = 0; it < CHUNK / 32; ++it) {
        // prefetch next 32-key tile (last iter overruns into adjacent ws; unused)
        bf16x8 Kn0 = *(const bf16x8*)&Kt[hb + off];
        bf16x8 Kn1 = *(const bf16x8*)&Kt[hb + off + 512];
        bf16x8 Vn0 = *(const bf16x8*)&Vt[hb + off];
        bf16x8 Vn1 = *(const bf16x8*)&Vt[hb + off + 512];
        off += 1024;

        // S^T = K . Q^T  (lane: S^T[key=(r&3)+8*(r>>2)+4*q2][q=l31], log2-domain)
        f32x16 acc = __builtin_amdgcn_mfma_f32_32x32x16_bf16(Kc0, Qf0, zc, 0, 0, 0);
        acc = __builtin_amdgcn_mfma_f32_32x32x16_bf16(Kc1, Qf1, acc, 0, 0, 0);

        float p[16];
#pragma unroll
        for (int r = 0; r < 16; ++r) { p[r] = __builtin_amdgcn_exp2f(acc[r]); ls += p[r]; }

        unsigned u[8], xu[8];
#pragma unroll
        for (int g = 0; g < 8; ++g) u[g] = pack_trunc(p[2 * g], p[2 * g + 1]);
#pragma unroll
        for (int g = 0; g < 8; ++g) xu[g] = (unsigned)__shfl_xor((int)u[g], 32, 64);

        uint4 f0, f1;
        f0.x = q2 ? xu[2] : u[0];  f0.y = q2 ? xu[3] : u[1];
        f0.z = q2 ? u[2]  : xu[0]; f0.w = q2 ? u[3]  : xu[1];
        f1.x = q2 ? xu[6] : u[4];  f1.y = q2 ? xu[7] : u[5];
        f1.z = q2 ? u[6]  : xu[4]; f1.w = q2 ? u[7]  : xu[5];
        bf16x8 Pf0 = __builtin_bit_cast(bf16x8, f0);
        bf16x8 Pf1 = __builtin_bit_cast(bf16x8, f1);

        Of = __builtin_amdgcn_mfma_f32_32x32x16_bf16(Vc0, Pf0, Of, 0, 0, 0);
        Of = __builtin_amdgcn_mfma_f32_32x32x16_bf16(Vc1, Pf1, Of, 0, 0, 0);

        Kc0 = Kn0; Kc1 = Kn1; Vc0 = Vn0; Vc1 = Vn1;
    }

    ls += __shfl_xor(ls, 32, 64);

    // Opart [n][32d]: reg group g covers d = 8g+4q2 .. +3 -> b64 stores
    const size_t obase = ((size_t)(s * 16 + bhp) * N_DIM + q) * 32;
#pragma unroll
    for (int g = 0; g < 4; ++g) {
        ushort4 st;
        st.x = (unsigned short)f32_to_bf16(Of[4 * g + 0]);
        st.y = (unsigned short)f32_to_bf16(Of[4 * g + 1]);
        st.z = (unsigned short)f32_to_bf16(Of[4 * g + 2]);
        st.w = (unsigned short)f32_to_bf16(Of[4 * g + 3]);
        *(ushort4*)&Opart[obase + 8 * g + 4 * q2] = st;
    }
    lpart[(size_t)(s * 16 + bhp) * N_DIM + q] = ls;
}

// ---------------------------------------------------------------------------
// Combine 4 split-K partials -> normalized AOt, swizzled [n][c] bf16.
// ---------------------------------------------------------------------------
__global__ __launch_bounds__(256) void combine4(
    const short* __restrict__ Opart, const float* __restrict__ lpart,
    short* __restrict__ AOt)
{
    const int n0 = blockIdx.x * 64;
    const int p  = blockIdx.y;          // b*8+h
    const int bb = p >> 3, hh = p & 7;
    const int t = threadIdx.x;
    __shared__ float linv[64];

    if (t < 64) {
        float sum = 0.f;
#pragma unroll
        for (int s = 0; s < 4; ++s)
            sum += lpart[(size_t)(s * 16 + p) * N_DIM + n0 + t];
        linv[t] = 1.f / sum;
    }
    __syncthreads();

    const int nl = t >> 2;              // 0..63
    const int dg = (t & 3) * 8;         // 0,8,16,24
    float a[8];
#pragma unroll
    for (int j = 0; j < 8; ++j) a[j] = 0.f;
#pragma unroll
    for (int s = 0; s < 4; ++s) {
        const size_t rb = ((size_t)(s * 16 + p) * N_DIM + n0 + nl) * 32 + dg;
        ushort4 u0 = *(const ushort4*)&Opart[rb];
        ushort4 u1 = *(const ushort4*)&Opart[rb + 4];
        a[0] += bf16_to_f32(u0.x); a[1] += bf16_to_f32(u0.y);
        a[2] += bf16_to_f32(u0.z); a[3] += bf16_to_f32(u0.w);
        a[4] += bf16_to_f32(u1.x); a[5] += bf16_to_f32(u1.y);
        a[6] += bf16_to_f32(u1.z); a[7] += bf16_to_f32(u1.w);
    }
    const float rl = linv[nl];
    ushort4 o0v, o1v;
    o0v.x = (unsigned short)f32_to_bf16(a[0] * rl);
    o0v.y = (unsigned short)f32_to_bf16(a[1] * rl);
    o0v.z = (unsigned short)f32_to_bf16(a[2] * rl);
    o0v.w = (unsigned short)f32_to_bf16(a[3] * rl);
    o1v.x = (unsigned short)f32_to_bf16(a[4] * rl);
    o1v.y = (unsigned short)f32_to_bf16(a[5] * rl);
    o1v.z = (unsigned short)f32_to_bf16(a[6] * rl);
    o1v.w = (unsigned short)f32_to_bf16(a[7] * rl);
    short* dst = &AOt[(size_t)bb * N_DIM * C_DIM + SWZ(n0 + nl, hh * 32 + dg)];
    *(ushort4*)dst = o0v;
    *(ushort4*)(dst + 4) = o1v;
}

// ---------------------------------------------------------------------------
// Out projection: r5/r7 split-K structure (main loop byte-identical).
// Epilogue (wave 0 only): bias + residual -> y16 (bf16) + fused GroupNorm
// partial stats via wave butterfly + 8 atomicAdds per block.
// ---------------------------------------------------------------------------
__global__ __launch_bounds__(256) void out_gemm(
    const short* __restrict__ OWsw, const short* __restrict__ AOt,
    const float* __restrict__ ob, const float* __restrict__ query,
    short* __restrict__ y16, float* __restrict__ gstats)
{
    const int t = threadIdx.x, w = t >> 6, lane = t & 63;
    const int q2 = lane >> 5, l31 = lane & 31;
    const int n0 = blockIdx.x * 32, o0 = blockIdx.y * 32, b = blockIdx.z;
    const short* B = AOt + (size_t)b * N_DIM * C_DIM;
    const int abase = (o0 >> 5) * 8192 + q2 * 256 + l31 * 8;
    const int bbase = (n0 >> 5) * 8192 + q2 * 256 + l31 * 8;

    f32x16 acc;
#pragma unroll
    for (int r = 0; r < 16; ++r) acc[r] = 0.f;

    const int kc0 = w * 64;
#pragma unroll
    for (int s2 = 0; s2 < 4; ++s2) {
        const int kc = kc0 + s2 * 16;
        bf16x8 af = *(const bf16x8*)&OWsw[abase + (kc >> 4) * 512];
        bf16x8 bf = *(const bf16x8*)&B[bbase + (kc >> 4) * 512];
        acc = __builtin_amdgcn_mfma_f32_32x32x16_bf16(af, bf, acc, 0, 0, 0);
    }

    __shared__ float red[3][64][17];
    if (w > 0) {
#pragma unroll
        for (int r = 0; r < 16; ++r) red[w - 1][lane][r] = acc[r];
    }
    __syncthreads();
    if (w == 0) {
#pragma unroll
        for (int r = 0; r < 16; ++r)
            acc[r] += red[0][lane][r] + red[1][lane][r] + red[2][lane][r];
        const size_t base = (size_t)b * C_DIM * N_DIM;
        float gs[4], gq[4];
#pragma unroll
        for (int j = 0; j < 4; ++j) { gs[j] = 0.f; gq[j] = 0.f; }
#pragma unroll
        for (int r = 0; r < 16; ++r) {
            const int o = o0 + (r & 3) + 8 * (r >> 2) + 4 * q2;
            const int n = n0 + l31;
            const size_t addr = base + (size_t)o * N_DIM + n;
            const float v = acc[r] + ob[o] + query[addr];
            y16[addr] = f32_to_bf16(v);
            gs[r >> 2] += v;
            gq[r >> 2] += v * v;
        }
#pragma unroll
        for (int offd = 1; offd < 64; offd <<= 1) {
#pragma unroll
            for (int j = 0; j < 4; ++j) {
                gs[j] += __shfl_xor(gs[j], offd, 64);
                gq[j] += __shfl_xor(gq[j], offd, 64);
            }
        }
        if (lane == 0) {
#pragma unroll
            for (int j = 0; j < 4; ++j) {
                const int grp = b * 32 + (o0 >> 3) + j;
                atomicAdd(&gstats[grp * 2 + 0], gs[j]);
                atomicAdd(&gstats[grp * 2 + 1], gq[j]);
            }
        }
    }
}

// ---------------------------------------------------------------------------
// GroupNorm apply: read y16 bf16, write fp32 d_out. Grid (32 g, 2 b, 4 sl).
// ---------------------------------------------------------------------------
__global__ __launch_bounds__(256) void gn_apply(
    const short* __restrict__ y16, const float* __restrict__ gstats,
    const float* __restrict__ gw, const float* __restrict__ gb,
    float* __restrict__ out)
{
    const int g = blockIdx.x, b = blockIdx.y, sl = blockIdx.z;
    const float s  = gstats[(b * 32 + g) * 2 + 0];
    const float qq = gstats[(b * 32 + g) * 2 + 1];
    const float mean = s * (1.f / 32768.f);
    const float var  = qq * (1.f / 32768.f) - mean * mean;
    const float rstd = rsqrtf(var + 1e-5f);

    const size_t base = ((size_t)b * C_DIM + (size_t)g * 8) * N_DIM + sl * 1024;
    const int t = threadIdx.x;
#pragma unroll
    for (int i = 0; i < 8; ++i) {
        const int idx = t + i * 256;          // 2048 4-elem slots over 8 rows
        const int row = idx >> 8, col = (idx & 255) * 4;
        const size_t a = base + (size_t)row * N_DIM + col;
        const float wv  = gw[g * 8 + row] * rstd;
        const float bb2 = gb[g * 8 + row];
        ushort4 u = *(const ushort4*)&y16[a];
        float4 v;
        v.x = (bf16_to_f32(u.x) - mean) * wv + bb2;
        v.y = (bf16_to_f32(u.y) - mean) * wv + bb2;
        v.z = (bf16_to_f32(u.z) - mean) * wv + bb2;
        v.w = (bf16_to_f32(u.w) - mean) * wv + bb2;
        *(float4*)&out[a] = v;
    }
}

// ---------------------------------------------------------------------------
extern "C" void kernel_launch(void* const* d_in, const int* in_sizes, int n_in,
                              void* d_out, int out_size, void* d_ws, size_t ws_size,
                              hipStream_t stream)
{
    const float* query = (const float*)d_in[0];
    const float* key   = (const float*)d_in[1];
    const float* q_w   = (const float*)d_in[2];
    const float* q_b   = (const float*)d_in[3];
    const float* k_w   = (const float*)d_in[4];
    const float* k_b   = (const float*)d_in[5];
    const float* v_w   = (const float*)d_in[6];
    const float* v_b   = (const float*)d_in[7];
    const float* o_w   = (const float*)d_in[8];
    const float* o_b   = (const float*)d_in[9];
    const float* gn_w  = (const float*)d_in[10];
    const float* gn_b  = (const float*)d_in[11];

    // ws (MiB): [0,0.5) Wsw  [0.75) gstats(512B)  [1,5) Qx (AOt aliases)
    // [5,9) Kx  [9,13) Qt  [13,17) Kt  [17,21) Vt
    // [21,37) Opart (y16 aliases after combine4)  [37,38) lpart
    char* wsb = (char*)d_ws;
    short* Wsw   = (short*)wsb;
    float* gstats= (float*)(wsb + (3u << 18));    // 0.75 MiB
    short* Qx    = (short*)(wsb + (1u  << 20));
    short* Kx    = (short*)(wsb + (5u  << 20));
    short* Qt    = (short*)(wsb + (9u  << 20));
    short* Kt    = (short*)(wsb + (13u << 20));
    short* Vt    = (short*)(wsb + (17u << 20));
    short* Opart = (short*)(wsb + (21u << 20));
    float* lpart = (float*)(wsb + (37u << 20));
    short* AOt   = Qx;            // Qx dead after qkv_gemm
    short* y16   = Opart;         // Opart dead after combine4

    // softmax scale 1/sqrt(32) * log2(e), folded into Q projection
    const float qscale = 0.17677669529663687f * 1.4426950408889634f;

    prep<<<dim3(64, 4, 5), 256, 0, stream>>>(query, key, q_w, k_w, v_w, o_w,
                                             Qx, Kx, Wsw, gstats);
    qkv_gemm<<<dim3(64, 4, 6), 256, 0, stream>>>(Wsw, Qx, Kx, q_b, k_b, v_b,
                                                 Qt, Kt, Vt, qscale);
    flash_mfma<<<dim3(32, 8, 8), 256, 0, stream>>>(Qt, Kt, Vt, Opart, lpart);
    combine4<<<dim3(64, 16), 256, 0, stream>>>(Opart, lpart, AOt);
    out_gemm<<<dim3(128, 8, 2), 256, 0, stream>>>(Wsw + 3 * 65536, AOt, o_b,
                                                  query, y16, gstats);
    gn_apply<<<dim3(32, 2, 4), 256, 0, stream>>>(y16, gstats, gn_w, gn_b,
                                                 (float*)d_out);
}

// Round 9
// 175.291 us; speedup vs baseline: 1.3507x; 1.3507x over previous
//
#include <hip/hip_runtime.h>
#include <math.h>

#define C_DIM 256
#define N_DIM 4096
#define NHEAD 8

using bf16x8 = __attribute__((ext_vector_type(8))) short;   // 8 bf16 = 4 VGPRs
using f32x16 = __attribute__((ext_vector_type(16))) float;  // 32x32 MFMA acc

__device__ __forceinline__ short f32_to_bf16(float a) {
    return (short)((__float_as_uint(a) + 0x8000u) >> 16);
}
__device__ __forceinline__ float bf16_to_f32(unsigned short u) {
    return __uint_as_float(((unsigned)u) << 16);
}
// lo16 = hi16(a), hi16 = hi16(b): single v_perm_b32 (truncation rounding)
__device__ __forceinline__ unsigned pack_trunc(float a, float b) {
    return __builtin_amdgcn_perm(__float_as_uint(b), __float_as_uint(a), 0x07060302u);
}

// Fragment-order ("swizzled") layout for 256-col planes, index in shorts.
// Per 32-row tile: [16 kc][2 q2][32 row][8 c]
__device__ __forceinline__ int SWZ(int m, int c) {
    return (m >> 5) * 8192 + (c >> 4) * 512 + ((c >> 3) & 1) * 256 + (m & 31) * 8 + (c & 7);
}

// ---------------------------------------------------------------------------
// prep: z<4 -> transpose query/key [c][n] fp32 -> swizzled bf16 [n][c] planes
//       z==4 -> convert 4 weight planes fp32 -> swizzled bf16; zero gstats
// ---------------------------------------------------------------------------
__global__ __launch_bounds__(256) void prep(
    const float* __restrict__ query, const float* __restrict__ key,
    const float* __restrict__ qw, const float* __restrict__ kw,
    const float* __restrict__ vw, const float* __restrict__ ow,
    short* __restrict__ Qx, short* __restrict__ Kx, short* __restrict__ Wsw,
    float* __restrict__ gstats)
{
    const int t = threadIdx.x;
    if (blockIdx.z == 4) {
        const int p = blockIdx.y;
        if (blockIdx.x == 0 && p == 0 && t < 128) gstats[t] = 0.f;
        const float* src = (p == 0) ? qw : (p == 1) ? kw : (p == 2) ? vw : ow;
        const int idx = (blockIdx.x * 256 + t) * 4;
        const int o = idx >> 8, c = idx & 255;
        float4 v = *(const float4*)&src[idx];
        short* dst = Wsw + p * 65536 + SWZ(o, c);
        dst[0] = f32_to_bf16(v.x); dst[1] = f32_to_bf16(v.y);
        dst[2] = f32_to_bf16(v.z); dst[3] = f32_to_bf16(v.w);
        return;
    }
    __shared__ short Ts[64][72];
    const int z = blockIdx.z;
    const float* in = (z < 2) ? query : key;
    short* out = ((z < 2) ? Qx : Kx) + (size_t)(z & 1) * N_DIM * C_DIM;
    const size_t ibase = (size_t)(z & 1) * C_DIM * N_DIM;
    const int n0 = blockIdx.x * 64, c0 = blockIdx.y * 64;
    const int cl = t >> 4, nl4 = (t & 15) * 4;
#pragma unroll
    for (int p = 0; p < 4; ++p) {
        const int c = cl + p * 16;
        float4 v = *(const float4*)&in[ibase + (size_t)(c0 + c) * N_DIM + n0 + nl4];
        Ts[nl4 + 0][c] = f32_to_bf16(v.x);
        Ts[nl4 + 1][c] = f32_to_bf16(v.y);
        Ts[nl4 + 2][c] = f32_to_bf16(v.z);
        Ts[nl4 + 3][c] = f32_to_bf16(v.w);
    }
    __syncthreads();
    const int nl = t >> 3, cg = t & 7;
#pragma unroll
    for (int half = 0; half < 2; ++half) {
        const int nloc = nl + half * 32;
        const int c = c0 + cg * 8;
        uint4 val = *(const uint4*)&Ts[nloc][cg * 8];
        *(uint4*)&out[SWZ(n0 + nloc, c)] = val;
    }
}

// ---------------------------------------------------------------------------
// QKV projection: z = proj*2 + batch. Block = 4 waves, 64n x 64o.
// proj 0/1 (Q/K): D = X.W^T -> swizzled head plane [n][d].
// proj 2   (V):   D = W.X   -> swizzled head plane [d-rows][k].
// ---------------------------------------------------------------------------
__global__ __launch_bounds__(256) void qkv_gemm(
    const short* __restrict__ Wsw, const short* __restrict__ Qx,
    const short* __restrict__ Kx,
    const float* __restrict__ q_b, const float* __restrict__ k_b,
    const float* __restrict__ v_b,
    short* __restrict__ Qt, short* __restrict__ Kt, short* __restrict__ Vt,
    float qscale)
{
    const int t = threadIdx.x, w = t >> 6, lane = t & 63;
    const int q2 = lane >> 5, l31 = lane & 31;
    const int proj = blockIdx.z >> 1, b = blockIdx.z & 1;
    const int n0 = blockIdx.x * 64 + (w >> 1) * 32;
    const int o0 = blockIdx.y * 64 + (w & 1) * 32;
    const short* X = ((proj == 0) ? Qx : Kx) + (size_t)b * N_DIM * C_DIM;
    const short* W = Wsw + proj * 65536;
    const float* bias = (proj == 0) ? q_b : (proj == 1) ? k_b : v_b;
    const int xbase = (n0 >> 5) * 8192 + q2 * 256 + l31 * 8;
    const int wbase = (o0 >> 5) * 8192 + q2 * 256 + l31 * 8;

    f32x16 acc;
#pragma unroll
    for (int r = 0; r < 16; ++r) acc[r] = 0.f;

#pragma unroll 4
    for (int kc = 0; kc < C_DIM; kc += 16) {
        bf16x8 xf = *(const bf16x8*)&X[xbase + (kc >> 4) * 512];
        bf16x8 wf = *(const bf16x8*)&W[wbase + (kc >> 4) * 512];
        if (proj == 2)
            acc = __builtin_amdgcn_mfma_f32_32x32x16_bf16(wf, xf, acc, 0, 0, 0);
        else
            acc = __builtin_amdgcn_mfma_f32_32x32x16_bf16(xf, wf, acc, 0, 0, 0);
    }

    const int head = o0 >> 5;
    if (proj < 2) {
        short* OH = ((proj == 0) ? Qt : Kt) + (size_t)(b * NHEAD + head) * N_DIM * 32;
        const float bi = bias[o0 + l31];
        const float sc = (proj == 0) ? qscale : 1.f;
        const int cbase = (n0 >> 5) * 1024 + (l31 >> 4) * 512 + ((l31 >> 3) & 1) * 256 + (l31 & 7);
#pragma unroll
        for (int r = 0; r < 16; ++r) {
            const int qs = (r & 3) + 8 * (r >> 2) + 4 * q2;
            OH[cbase + qs * 8] = f32_to_bf16((acc[r] + bi) * sc);
        }
    } else {
        short* VH = Vt + (size_t)(b * NHEAD + head) * N_DIM * 32;
        const int kbase = (n0 >> 5) * 1024 + (l31 >> 4) * 512 + ((l31 >> 3) & 1) * 256 + (l31 & 7);
#pragma unroll
        for (int r = 0; r < 16; ++r) {
            const int ds = (r & 3) + 8 * (r >> 2) + 4 * q2;
            VH[kbase + ds * 8] = f32_to_bf16(acc[r] + bias[o0 + ds]);
        }
    }
}

// ---------------------------------------------------------------------------
// Flash attention, swizzled operands, split-4 over keys. Byte-identical to
// the r7 kernel verified at ~63 us.
// ---------------------------------------------------------------------------
__global__ __launch_bounds__(256) void flash_mfma(
    const short* __restrict__ Qt, const short* __restrict__ Kt,
    const short* __restrict__ Vt, short* __restrict__ Opart,
    float* __restrict__ lpart)
{
    const int n0 = blockIdx.x * 128;
    const int h  = blockIdx.y;
    const int z  = blockIdx.z;
    const int b  = z >> 2, s = z & 3;
    const int CHUNK = N_DIM / 4;
    const int t = threadIdx.x, w = t >> 6, lane = t & 63;
    const int q2 = lane >> 5, l31 = lane & 31;
    const int q  = n0 + w * 32 + l31;
    const int bhp = b * NHEAD + h;
    const size_t hb = (size_t)bhp * N_DIM * 32;

    const int qoff = (q >> 5) * 1024 + q2 * 256 + (q & 31) * 8;
    bf16x8 Qf0 = *(const bf16x8*)&Qt[hb + qoff];
    bf16x8 Qf1 = *(const bf16x8*)&Qt[hb + qoff + 512];

    int off = ((s * CHUNK) >> 5) * 1024 + q2 * 256 + l31 * 8;
    bf16x8 Kc0 = *(const bf16x8*)&Kt[hb + off];
    bf16x8 Kc1 = *(const bf16x8*)&Kt[hb + off + 512];
    bf16x8 Vc0 = *(const bf16x8*)&Vt[hb + off];
    bf16x8 Vc1 = *(const bf16x8*)&Vt[hb + off + 512];
    off += 1024;

    f32x16 Of;
#pragma unroll
    for (int r = 0; r < 16; ++r) Of[r] = 0.f;
    float ls = 0.f;

    for (int it = 0; it < CHUNK / 32; ++it) {
        // prefetch next 32-key tile (last iter overruns into adjacent ws; unused)
        bf16x8 Kn0 = *(const bf16x8*)&Kt[hb + off];
        bf16x8 Kn1 = *(const bf16x8*)&Kt[hb + off + 512];
        bf16x8 Vn0 = *(const bf16x8*)&Vt[hb + off];
        bf16x8 Vn1 = *(const bf16x8*)&Vt[hb + off + 512];
        off += 1024;

        // S^T = K . Q^T  (lane: S^T[key=(r&3)+8*(r>>2)+4*q2][q=l31], log2-domain)
        f32x16 acc;
#pragma unroll
        for (int r = 0; r < 16; ++r) acc[r] = 0.f;
        acc = __builtin_amdgcn_mfma_f32_32x32x16_bf16(Kc0, Qf0, acc, 0, 0, 0);
        acc = __builtin_amdgcn_mfma_f32_32x32x16_bf16(Kc1, Qf1, acc, 0, 0, 0);

        float p[16];
#pragma unroll
        for (int r = 0; r < 16; ++r) { p[r] = __builtin_amdgcn_exp2f(acc[r]); ls += p[r]; }

        unsigned u[8], xu[8];
#pragma unroll
        for (int g = 0; g < 8; ++g) u[g] = pack_trunc(p[2 * g], p[2 * g + 1]);
#pragma unroll
        for (int g = 0; g < 8; ++g) xu[g] = (unsigned)__shfl_xor((int)u[g], 32, 64);

        uint4 f0, f1;
        f0.x = q2 ? xu[2] : u[0];  f0.y = q2 ? xu[3] : u[1];
        f0.z = q2 ? u[2]  : xu[0]; f0.w = q2 ? u[3]  : xu[1];
        f1.x = q2 ? xu[6] : u[4];  f1.y = q2 ? xu[7] : u[5];
        f1.z = q2 ? u[6]  : xu[4]; f1.w = q2 ? u[7]  : xu[5];
        bf16x8 Pf0 = __builtin_bit_cast(bf16x8, f0);
        bf16x8 Pf1 = __builtin_bit_cast(bf16x8, f1);

        Of = __builtin_amdgcn_mfma_f32_32x32x16_bf16(Vc0, Pf0, Of, 0, 0, 0);
        Of = __builtin_amdgcn_mfma_f32_32x32x16_bf16(Vc1, Pf1, Of, 0, 0, 0);

        Kc0 = Kn0; Kc1 = Kn1; Vc0 = Vn0; Vc1 = Vn1;
    }

    ls += __shfl_xor(ls, 32, 64);

    // Opart [n][32d]: reg group g covers d = 8g+4q2 .. +3 -> b64 stores
    const size_t obase = ((size_t)(s * 16 + bhp) * N_DIM + q) * 32;
#pragma unroll
    for (int g = 0; g < 4; ++g) {
        ushort4 st;
        st.x = (unsigned short)f32_to_bf16(Of[4 * g + 0]);
        st.y = (unsigned short)f32_to_bf16(Of[4 * g + 1]);
        st.z = (unsigned short)f32_to_bf16(Of[4 * g + 2]);
        st.w = (unsigned short)f32_to_bf16(Of[4 * g + 3]);
        *(ushort4*)&Opart[obase + 8 * g + 4 * q2] = st;
    }
    lpart[(size_t)(s * 16 + bhp) * N_DIM + q] = ls;
}

// ---------------------------------------------------------------------------
// Combine 4 split-K partials -> normalized AOt, swizzled [n][c] bf16.
// ---------------------------------------------------------------------------
__global__ __launch_bounds__(256) void combine4(
    const short* __restrict__ Opart, const float* __restrict__ lpart,
    short* __restrict__ AOt)
{
    const int n0 = blockIdx.x * 64;
    const int p  = blockIdx.y;          // b*8+h
    const int bb = p >> 3, hh = p & 7;
    const int t = threadIdx.x;
    __shared__ float linv[64];

    if (t < 64) {
        float sum = 0.f;
#pragma unroll
        for (int s = 0; s < 4; ++s)
            sum += lpart[(size_t)(s * 16 + p) * N_DIM + n0 + t];
        linv[t] = 1.f / sum;
    }
    __syncthreads();

    const int nl = t >> 2;              // 0..63
    const int dg = (t & 3) * 8;         // 0,8,16,24
    float a[8];
#pragma unroll
    for (int j = 0; j < 8; ++j) a[j] = 0.f;
#pragma unroll
    for (int s = 0; s < 4; ++s) {
        const size_t rb = ((size_t)(s * 16 + p) * N_DIM + n0 + nl) * 32 + dg;
        ushort4 u0 = *(const ushort4*)&Opart[rb];
        ushort4 u1 = *(const ushort4*)&Opart[rb + 4];
        a[0] += bf16_to_f32(u0.x); a[1] += bf16_to_f32(u0.y);
        a[2] += bf16_to_f32(u0.z); a[3] += bf16_to_f32(u0.w);
        a[4] += bf16_to_f32(u1.x); a[5] += bf16_to_f32(u1.y);
        a[6] += bf16_to_f32(u1.z); a[7] += bf16_to_f32(u1.w);
    }
    const float rl = linv[nl];
    ushort4 o0v, o1v;
    o0v.x = (unsigned short)f32_to_bf16(a[0] * rl);
    o0v.y = (unsigned short)f32_to_bf16(a[1] * rl);
    o0v.z = (unsigned short)f32_to_bf16(a[2] * rl);
    o0v.w = (unsigned short)f32_to_bf16(a[3] * rl);
    o1v.x = (unsigned short)f32_to_bf16(a[4] * rl);
    o1v.y = (unsigned short)f32_to_bf16(a[5] * rl);
    o1v.z = (unsigned short)f32_to_bf16(a[6] * rl);
    o1v.w = (unsigned short)f32_to_bf16(a[7] * rl);
    short* dst = &AOt[(size_t)bb * N_DIM * C_DIM + SWZ(n0 + nl, hh * 32 + dg)];
    *(ushort4*)dst = o0v;
    *(ushort4*)(dst + 4) = o1v;
}

// ---------------------------------------------------------------------------
// Out projection: r7 structure (split-K over 4 waves + LDS reduce, NO
// atomics). Only change vs r7: y written as bf16 (y16).
// ---------------------------------------------------------------------------
__global__ __launch_bounds__(256) void out_gemm(
    const short* __restrict__ OWsw, const short* __restrict__ AOt,
    const float* __restrict__ ob, const float* __restrict__ query,
    short* __restrict__ y16)
{
    const int t = threadIdx.x, w = t >> 6, lane = t & 63;
    const int q2 = lane >> 5, l31 = lane & 31;
    const int n0 = blockIdx.x * 32, o0 = blockIdx.y * 32, b = blockIdx.z;
    const short* B = AOt + (size_t)b * N_DIM * C_DIM;
    const int abase = (o0 >> 5) * 8192 + q2 * 256 + l31 * 8;
    const int bbase = (n0 >> 5) * 8192 + q2 * 256 + l31 * 8;

    f32x16 acc;
#pragma unroll
    for (int r = 0; r < 16; ++r) acc[r] = 0.f;

    const int kc0 = w * 64;
#pragma unroll
    for (int s2 = 0; s2 < 4; ++s2) {
        const int kc = kc0 + s2 * 16;
        bf16x8 af = *(const bf16x8*)&OWsw[abase + (kc >> 4) * 512];
        bf16x8 bf = *(const bf16x8*)&B[bbase + (kc >> 4) * 512];
        acc = __builtin_amdgcn_mfma_f32_32x32x16_bf16(af, bf, acc, 0, 0, 0);
    }

    __shared__ float red[3][64][17];
    if (w > 0) {
#pragma unroll
        for (int r = 0; r < 16; ++r) red[w - 1][lane][r] = acc[r];
    }
    __syncthreads();
    if (w == 0) {
#pragma unroll
        for (int r = 0; r < 16; ++r)
            acc[r] += red[0][lane][r] + red[1][lane][r] + red[2][lane][r];
        const size_t base = (size_t)b * C_DIM * N_DIM;
#pragma unroll
        for (int r = 0; r < 16; ++r) {
            const int o = o0 + (r & 3) + 8 * (r >> 2) + 4 * q2;
            const int n = n0 + l31;
            const size_t addr = base + (size_t)o * N_DIM + n;
            y16[addr] = f32_to_bf16(acc[r] + ob[o] + query[addr]);
        }
    }
}

// ---------------------------------------------------------------------------
// GroupNorm stats from y16 (bf16): grid (32 g, 2 b, 4 slice). Partial
// sum/sumsq per block, 2 atomicAdds per block (512 total — benign).
// ---------------------------------------------------------------------------
__global__ __launch_bounds__(256) void gn_stats(
    const short* __restrict__ y16, float* __restrict__ gstats)
{
    const int g = blockIdx.x, b = blockIdx.y, sl = blockIdx.z;
    const size_t base = ((size_t)b * C_DIM + (size_t)g * 8) * N_DIM + sl * 1024;
    const int t = threadIdx.x;
    float sum = 0.f, sumsq = 0.f;
#pragma unroll
    for (int i = 0; i < 8; ++i) {
        const int idx = t + i * 256;          // 2048 4-elem slots over 8 rows
        const int row = idx >> 8, col = (idx & 255) * 4;
        ushort4 u = *(const ushort4*)&y16[base + (size_t)row * N_DIM + col];
        const float v0 = bf16_to_f32(u.x), v1 = bf16_to_f32(u.y);
        const float v2 = bf16_to_f32(u.z), v3 = bf16_to_f32(u.w);
        sum   += v0 + v1 + v2 + v3;
        sumsq += v0 * v0 + v1 * v1 + v2 * v2 + v3 * v3;
    }
#pragma unroll
    for (int off = 1; off < 64; off <<= 1) {
        sum   += __shfl_xor(sum, off, 64);
        sumsq += __shfl_xor(sumsq, off, 64);
    }
    __shared__ float red[8];
    const int wid = t >> 6;
    if ((t & 63) == 0) { red[wid] = sum; red[4 + wid] = sumsq; }
    __syncthreads();
    if (t == 0) {
        const int grp = b * 32 + g;
        atomicAdd(&gstats[grp * 2 + 0], red[0] + red[1] + red[2] + red[3]);
        atomicAdd(&gstats[grp * 2 + 1], red[4] + red[5] + red[6] + red[7]);
    }
}

// ---------------------------------------------------------------------------
// GroupNorm apply: read y16 bf16, write fp32 d_out. Grid (32 g, 2 b, 4 sl).
// ---------------------------------------------------------------------------
__global__ __launch_bounds__(256) void gn_apply(
    const short* __restrict__ y16, const float* __restrict__ gstats,
    const float* __restrict__ gw, const float* __restrict__ gb,
    float* __restrict__ out)
{
    const int g = blockIdx.x, b = blockIdx.y, sl = blockIdx.z;
    const float s  = gstats[(b * 32 + g) * 2 + 0];
    const float qq = gstats[(b * 32 + g) * 2 + 1];
    const float mean = s * (1.f / 32768.f);
    const float var  = qq * (1.f / 32768.f) - mean * mean;
    const float rstd = rsqrtf(var + 1e-5f);

    const size_t base = ((size_t)b * C_DIM + (size_t)g * 8) * N_DIM + sl * 1024;
    const int t = threadIdx.x;
#pragma unroll
    for (int i = 0; i < 8; ++i) {
        const int idx = t + i * 256;          // 2048 4-elem slots over 8 rows
        const int row = idx >> 8, col = (idx & 255) * 4;
        const size_t a = base + (size_t)row * N_DIM + col;
        const float wv  = gw[g * 8 + row] * rstd;
        const float bb2 = gb[g * 8 + row];
        ushort4 u = *(const ushort4*)&y16[a];
        float4 v;
        v.x = (bf16_to_f32(u.x) - mean) * wv + bb2;
        v.y = (bf16_to_f32(u.y) - mean) * wv + bb2;
        v.z = (bf16_to_f32(u.z) - mean) * wv + bb2;
        v.w = (bf16_to_f32(u.w) - mean) * wv + bb2;
        *(float4*)&out[a] = v;
    }
}

// ---------------------------------------------------------------------------
extern "C" void kernel_launch(void* const* d_in, const int* in_sizes, int n_in,
                              void* d_out, int out_size, void* d_ws, size_t ws_size,
                              hipStream_t stream)
{
    const float* query = (const float*)d_in[0];
    const float* key   = (const float*)d_in[1];
    const float* q_w   = (const float*)d_in[2];
    const float* q_b   = (const float*)d_in[3];
    const float* k_w   = (const float*)d_in[4];
    const float* k_b   = (const float*)d_in[5];
    const float* v_w   = (const float*)d_in[6];
    const float* v_b   = (const float*)d_in[7];
    const float* o_w   = (const float*)d_in[8];
    const float* o_b   = (const float*)d_in[9];
    const float* gn_w  = (const float*)d_in[10];
    const float* gn_b  = (const float*)d_in[11];

    // ws (MiB): [0,0.5) Wsw  [0.75) gstats(512B)  [1,5) Qx (AOt aliases)
    // [5,9) Kx  [9,13) Qt  [13,17) Kt  [17,21) Vt
    // [21,37) Opart (y16 aliases after combine4)  [37,38) lpart
    char* wsb = (char*)d_ws;
    short* Wsw   = (short*)wsb;
    float* gstats= (float*)(wsb + (3u << 18));    // 0.75 MiB
    short* Qx    = (short*)(wsb + (1u  << 20));
    short* Kx    = (short*)(wsb + (5u  << 20));
    short* Qt    = (short*)(wsb + (9u  << 20));
    short* Kt    = (short*)(wsb + (13u << 20));
    short* Vt    = (short*)(wsb + (17u << 20));
    short* Opart = (short*)(wsb + (21u << 20));
    float* lpart = (float*)(wsb + (37u << 20));
    short* AOt   = Qx;            // Qx dead after qkv_gemm
    short* y16   = Opart;         // Opart dead after combine4

    // softmax scale 1/sqrt(32) * log2(e), folded into Q projection
    const float qscale = 0.17677669529663687f * 1.4426950408889634f;

    prep<<<dim3(64, 4, 5), 256, 0, stream>>>(query, key, q_w, k_w, v_w, o_w,
                                             Qx, Kx, Wsw, gstats);
    qkv_gemm<<<dim3(64, 4, 6), 256, 0, stream>>>(Wsw, Qx, Kx, q_b, k_b, v_b,
                                                 Qt, Kt, Vt, qscale);
    flash_mfma<<<dim3(32, 8, 8), 256, 0, stream>>>(Qt, Kt, Vt, Opart, lpart);
    combine4<<<dim3(64, 16), 256, 0, stream>>>(Opart, lpart, AOt);
    out_gemm<<<dim3(128, 8, 2), 256, 0, stream>>>(Wsw + 3 * 65536, AOt, o_b,
                                                  query, y16);
    gn_stats<<<dim3(32, 2, 4), 256, 0, stream>>>(y16, gstats);
    gn_apply<<<dim3(32, 2, 4), 256, 0, stream>>>(y16, gstats, gn_w, gn_b,
                                                 (float*)d_out);
}